// Round 1
// baseline (664.471 us; speedup 1.0000x reference)
//
#include <hip/hip_runtime.h>
#include <hip/hip_bf16.h>
#include <cstdint>
#include <cstddef>

// Problem dims
#define TN   16384   // t (feature time)
#define TFR  32768   // frame_level time
#define K1   512     // in channels
#define M12  1536    // lr (1024) + cur (512) combined out channels
#define M3   512     // final out channels
#define K3   1536    // conv3 effective K (feat 1024 + fm_short 512; sampled folded into const)

typedef __attribute__((ext_vector_type(8))) short short8;
typedef __attribute__((ext_vector_type(4))) float f32x4;

__device__ __forceinline__ unsigned short f2bf(float f) {
  __hip_bfloat16 h = __float2bfloat16(f);
  unsigned short u; __builtin_memcpy(&u, &h, 2); return u;
}
__device__ __forceinline__ float bf2f(unsigned short u) {
  __hip_bfloat16 h; __builtin_memcpy(&h, &u, 2); return __bfloat162float(h);
}

// ---------------------------------------------------------------------------
// Weight prep: w12 = [lr_w; cur_w] bf16 [1536][512]; w3 = prop_w[:,512:2048] bf16
// [512][1536]; b12 = [lr_b; cur_b]
// ---------------------------------------------------------------------------
__global__ void prep_w(const float* __restrict__ cur_w, const float* __restrict__ cur_b,
                       const float* __restrict__ lr_w, const float* __restrict__ lr_b,
                       const float* __restrict__ prop_w,
                       unsigned short* __restrict__ w12, unsigned short* __restrict__ w3,
                       float* __restrict__ b12) {
  int i = blockIdx.x * blockDim.x + threadIdx.x;   // 0 .. 786431
  // w12
  {
    int r = i >> 9, k = i & 511;
    float v = (r < 1024) ? lr_w[i] : cur_w[(r - 1024) * 512 + k];
    w12[i] = f2bf(v);
  }
  // w3
  {
    int o = i / 1536, c = i - o * 1536;
    w3[i] = f2bf(prop_w[o * 2048 + 512 + c]);
  }
  if (i < M12) b12[i] = (i < 1024) ? lr_b[i] : cur_b[i - 1024];
}

// ---------------------------------------------------------------------------
// Partial per-frame max over channel chunks: pm[chunk][t], 8 chunks of 64 ch
// ---------------------------------------------------------------------------
__global__ void maxred(const float* __restrict__ fr, float* __restrict__ pm) {
  int b = blockIdx.x;             // 1024 blocks
  int cchunk = b >> 7;            // 0..7
  int t = (b & 127) * 256 + threadIdx.x;
  int cs = cchunk * 64;
  float mx = -3.4e38f;
#pragma unroll 8
  for (int c = cs; c < cs + 64; ++c) mx = fmaxf(mx, fr[(size_t)c * TFR + t]);
  pm[(size_t)cchunk * TFR + t] = mx;
}

// ---------------------------------------------------------------------------
// Single-block scan + inverse-CDF pick: idx = first t with c[t] == min(c)
// ---------------------------------------------------------------------------
__global__ __launch_bounds__(1024) void scan_pick(const float* __restrict__ pm,
                                                  int* __restrict__ idxp) {
  __shared__ float sA[1024], sB[1024];
  __shared__ int si[1024];
  int tid = threadIdx.x;
  int base = tid * 32;
  float mv[32];
  float lsum = 0.f;
#pragma unroll
  for (int j = 0; j < 32; ++j) {
    int t = base + j;
    float mx = pm[t];
#pragma unroll
    for (int p = 1; p < 8; ++p) mx = fmaxf(mx, pm[(size_t)p * TFR + t]);
    mv[j] = mx; lsum += mx;
  }
  sA[tid] = lsum; __syncthreads();
  float* a = sA; float* b = sB;
  for (int d = 1; d < 1024; d <<= 1) {
    float v = a[tid];
    if (tid >= d) v += a[tid - d];
    b[tid] = v; __syncthreads();
    float* tmp = a; a = b; b = tmp;
  }
  float total = a[1023];
  float prev = (tid > 0) ? a[tid - 1] : 0.f;
  float inv = 1.0f / total;
  int cloc[32];
  int minc = 0x7fffffff;
  float run = prev;
#pragma unroll
  for (int j = 0; j < 32; ++j) {
    run += mv[j];
    int cj = (int)(run * inv * 16384.0f);   // trunc toward 0 (cdf >= 0)
    cloc[j] = cj;
    if (cj >= 0 && cj < minc) minc = cj;
  }
  si[tid] = minc; __syncthreads();
  for (int d = 512; d >= 1; d >>= 1) { if (tid < d) si[tid] = min(si[tid], si[tid + d]); __syncthreads(); }
  int cur = si[0]; __syncthreads();
  int cand = 0x7fffffff;
#pragma unroll
  for (int j = 0; j < 32; ++j)
    if (cloc[j] == cur && cand == 0x7fffffff) cand = base + j;
  si[tid] = cand; __syncthreads();
  for (int d = 512; d >= 1; d >>= 1) { if (tid < d) si[tid] = min(si[tid], si[tid + d]); __syncthreads(); }
  if (tid == 0) idxp[0] = si[0];
}

// ---------------------------------------------------------------------------
// const[o] = prop_b[o] + sum_{c<512} prop_w[o][c] * frame[c][idx]
// ---------------------------------------------------------------------------
__global__ void sample_const(const float* __restrict__ prop_w, const float* __restrict__ prop_b,
                             const float* __restrict__ frame, const int* __restrict__ idxp,
                             float* __restrict__ constb) {
  int o = blockIdx.x * blockDim.x + threadIdx.x;
  if (o >= 512) return;
  int idx = idxp[0];
  float acc = prop_b[o];
  for (int c = 0; c < 512; ++c)
    acc += prop_w[o * 2048 + c] * frame[(size_t)c * TFR + idx];
  constb[o] = acc;
}

// ---------------------------------------------------------------------------
// Transpose feature [512][16384] f32 -> featT [16384][512] bf16
// ---------------------------------------------------------------------------
__global__ __launch_bounds__(256) void transpose_feat(const float* __restrict__ X,
                                                      unsigned short* __restrict__ XT) {
  __shared__ float tile[64][65];
  int t0 = blockIdx.x * 64, c0 = blockIdx.y * 64;
  int tx = threadIdx.x & 63, ty = threadIdx.x >> 6;
#pragma unroll
  for (int r = 0; r < 16; ++r) {
    int c = c0 + ty * 16 + r;
    tile[ty * 16 + r][tx] = X[(size_t)c * TN + t0 + tx];
  }
  __syncthreads();
#pragma unroll
  for (int r = 0; r < 16; ++r) {
    int t = t0 + ty * 16 + r;
    XT[(size_t)t * K1 + c0 + tx] = f2bf(tile[tx][ty * 16 + r]);
  }
}

// ---------------------------------------------------------------------------
// GEMM: Y[t][c] = sum_k XT[t][k] * Wb[c][k] + bias[c]   (bf16 in, bf16 out)
// also accumulates per-group (sum, sumsq) of the fp32 pre-store values.
// A-frag: rows=t (lane&15), k-run of 8 at (lane>>4)*8. B-frag: cols=c (lane&15).
// C/D: col=lane&15, row=(lane>>4)*4+q  [verified gfx950 mapping]
// ---------------------------------------------------------------------------
__global__ __launch_bounds__(256) void gemm_bf16(
    const unsigned short* __restrict__ XT,   // [T][K]
    const unsigned short* __restrict__ Wb,   // [M][K]
    const float* __restrict__ bias,          // [M]
    unsigned short* __restrict__ Y,          // [T][M]
    float* __restrict__ gsum, float* __restrict__ gss,
    int K, int M, int mode)                  // mode 0: gn2|gn1 combined; 1: gn3
{
  __shared__ __attribute__((aligned(16))) unsigned short As[128 * 64];
  __shared__ __attribute__((aligned(16))) unsigned short Bs[128 * 64];
  const int tid = threadIdx.x;
  const int lane = tid & 63;
  const int w = tid >> 6;
  const int t0 = blockIdx.x * 128;
  const int c0 = blockIdx.y * 128;

  f32x4 acc[4][4] = {};
  const int lrow = lane & 15;
  const int lk = (lane >> 4) * 8;
  const int tb = (w >> 1) * 64, cb = (w & 1) * 64;

  for (int ks = 0; ks < K; ks += 64) {
    __syncthreads();
#pragma unroll
    for (int op = 0; op < 4; ++op) {
      int L = op * 4096 + tid * 16;       // byte offset within 16KB tile
      int row = L >> 7;                   // 128B per row (64 bf16)
      int ko = (L & 127) >> 1;
      *(short8*)((char*)As + L) = *(const short8*)(XT + (size_t)(t0 + row) * K + ks + ko);
      *(short8*)((char*)Bs + L) = *(const short8*)(Wb + (size_t)(c0 + row) * K + ks + ko);
    }
    __syncthreads();
#pragma unroll
    for (int kk = 0; kk < 64; kk += 32) {
      short8 a[4], b[4];
#pragma unroll
      for (int i = 0; i < 4; ++i) a[i] = *(const short8*)&As[(tb + i * 16 + lrow) * 64 + kk + lk];
#pragma unroll
      for (int j = 0; j < 4; ++j) b[j] = *(const short8*)&Bs[(cb + j * 16 + lrow) * 64 + kk + lk];
#pragma unroll
      for (int i = 0; i < 4; ++i)
#pragma unroll
        for (int j = 0; j < 4; ++j)
          acc[i][j] = __builtin_amdgcn_mfma_f32_16x16x32_bf16(a[i], b[j], acc[i][j], 0, 0, 0);
    }
  }

  // epilogue: bias, bf16 store, group stats
  const int lq = (lane >> 4) * 4;
#pragma unroll
  for (int j = 0; j < 4; ++j) {
    int c = c0 + cb + j * 16 + lrow;
    float bv = bias[c];
    float s = 0.f, ss = 0.f;
#pragma unroll
    for (int i = 0; i < 4; ++i) {
#pragma unroll
      for (int q = 0; q < 4; ++q) {
        float v = acc[i][j][q] + bv;
        s += v; ss += v * v;
        int t = t0 + tb + i * 16 + lq + q;
        Y[(size_t)t * M + c] = f2bf(v);
      }
    }
#pragma unroll
    for (int off = 32; off >= 1; off >>= 1) { s += __shfl_xor(s, off); ss += __shfl_xor(ss, off); }
    if (lane == 0) {
      int g = (mode == 0) ? ((c < 1024) ? (c >> 5) : (32 + ((c - 1024) >> 4))) : (c >> 4);
      atomicAdd(&gsum[g], s);
      atomicAdd(&gss[g], ss);
    }
  }
}

// ---------------------------------------------------------------------------
// Normalize conv1+2 output: in-place relu(norm(yz)) (bf16, GEMM3 input) and
// transposed f32 write of channels <1024 (feat) to d_out.
// ---------------------------------------------------------------------------
__global__ __launch_bounds__(256) void norm12(
    unsigned short* __restrict__ yz,      // [T][1536]
    const float* __restrict__ gsum, const float* __restrict__ gss,
    const float* __restrict__ gn1_g, const float* __restrict__ gn1_b,
    const float* __restrict__ gn2_g, const float* __restrict__ gn2_b,
    float* __restrict__ dfeat) {          // [1024][16384]
  __shared__ float tile[64][65];
  int t0 = blockIdx.x * 64, c0 = blockIdx.y * 64;
  int tx = threadIdx.x & 63, ty = threadIdx.x >> 6;
  int c = c0 + tx;
  int g; float gm, gb, cnt;
  if (c < 1024) { g = c >> 5;               gm = gn2_g[c];        gb = gn2_b[c];        cnt = 524288.f; }
  else          { g = 32 + ((c - 1024) >> 4); gm = gn1_g[c - 1024]; gb = gn1_b[c - 1024]; cnt = 262144.f; }
  float mean = gsum[g] / cnt;
  float var = gss[g] / cnt - mean * mean;
  float rstd = rsqrtf(var + 1e-5f);
#pragma unroll
  for (int r = 0; r < 16; ++r) {
    int t = t0 + ty * 16 + r;
    size_t off = (size_t)t * 1536 + c;
    float v = bf2f(yz[off]);
    v = (v - mean) * rstd * gm + gb;
    v = fmaxf(v, 0.f);
    yz[off] = f2bf(v);
    tile[tx][ty * 16 + r] = v;
  }
  if (c0 < 1024) {
    __syncthreads();
#pragma unroll
    for (int r = 0; r < 16; ++r) {
      int cc = c0 + ty * 16 + r;
      dfeat[(size_t)cc * TN + t0 + tx] = tile[ty * 16 + r][tx];
    }
  }
}

// ---------------------------------------------------------------------------
// Normalize conv3 output -> mixed (f32, transposed to [512][16384])
// ---------------------------------------------------------------------------
__global__ __launch_bounds__(256) void norm3(
    const unsigned short* __restrict__ y3,  // [T][512]
    const float* __restrict__ gsum, const float* __restrict__ gss,
    const float* __restrict__ g3g, const float* __restrict__ g3b,
    float* __restrict__ dmix) {             // [512][16384]
  __shared__ float tile[64][65];
  int t0 = blockIdx.x * 64, c0 = blockIdx.y * 64;
  int tx = threadIdx.x & 63, ty = threadIdx.x >> 6;
  int c = c0 + tx;
  int g = c >> 4;
  float mean = gsum[g] / 262144.f;
  float var = gss[g] / 262144.f - mean * mean;
  float rstd = rsqrtf(var + 1e-5f);
  float gm = g3g[c], gb = g3b[c];
#pragma unroll
  for (int r = 0; r < 16; ++r) {
    int t = t0 + ty * 16 + r;
    float v = bf2f(y3[(size_t)t * 512 + c]);
    v = (v - mean) * rstd * gm + gb;
    tile[tx][ty * 16 + r] = fmaxf(v, 0.f);
  }
  __syncthreads();
#pragma unroll
  for (int r = 0; r < 16; ++r) {
    int cc = c0 + ty * 16 + r;
    dmix[(size_t)cc * TN + t0 + tx] = tile[ty * 16 + r][tx];
  }
}

// ---------------------------------------------------------------------------
extern "C" void kernel_launch(void* const* d_in, const int* in_sizes, int n_in,
                              void* d_out, int out_size, void* d_ws, size_t ws_size,
                              hipStream_t stream) {
  const float* feature = (const float*)d_in[0];
  const float* frame   = (const float*)d_in[1];
  const float* cur_w   = (const float*)d_in[2];
  const float* cur_b   = (const float*)d_in[3];
  const float* gn1_g   = (const float*)d_in[4];
  const float* gn1_b   = (const float*)d_in[5];
  const float* lr_w    = (const float*)d_in[6];
  const float* lr_b    = (const float*)d_in[7];
  const float* gn2_g   = (const float*)d_in[8];
  const float* gn2_b   = (const float*)d_in[9];
  const float* prop_w  = (const float*)d_in[10];
  const float* prop_b  = (const float*)d_in[11];
  const float* gn3_g   = (const float*)d_in[12];
  const float* gn3_b   = (const float*)d_in[13];

  char* ws = (char*)d_ws;
  // ws layout (bytes)
  unsigned short* yzT   = (unsigned short*)(ws);                 // 50331648: conv12 raw -> z (in-place)
  unsigned short* featT = (unsigned short*)(ws + 50331648);      // 16777216: featT, reused as y3T
  unsigned short* y3T   = featT;
  unsigned short* w12   = (unsigned short*)(ws + 67108864);      // 1572864
  unsigned short* w3    = (unsigned short*)(ws + 68681728);      // 1572864
  float* b12    = (float*)(ws + 70254592);                       // 6144
  float* pm     = (float*)(ws + 70260736);                       // 1048576
  float* s12    = (float*)(ws + 71309312);                       // 64+64 f32
  float* ss12   = s12 + 64;
  float* s3     = (float*)(ws + 71309824);                       // 32+32 f32
  float* ss3    = s3 + 32;
  float* constb = (float*)(ws + 71310080);                       // 2048
  int*   idxp   = (int*)(ws + 71312128);

  float* dmix  = (float*)d_out;                 // [512][16384]
  float* dfeat = (float*)d_out + 8388608;       // [1024][16384]

  // zero the stats accumulators (ws is poisoned each launch)
  hipMemsetAsync(ws + 71309312, 0, 768, stream);

  hipLaunchKernelGGL(prep_w, dim3(3072), dim3(256), 0, stream,
                     cur_w, cur_b, lr_w, lr_b, prop_w, w12, w3, b12);
  hipLaunchKernelGGL(maxred, dim3(1024), dim3(256), 0, stream, frame, pm);
  hipLaunchKernelGGL(scan_pick, dim3(1), dim3(1024), 0, stream, pm, idxp);
  hipLaunchKernelGGL(transpose_feat, dim3(256, 8), dim3(256), 0, stream, feature, featT);
  hipLaunchKernelGGL(sample_const, dim3(2), dim3(256), 0, stream,
                     prop_w, prop_b, frame, idxp, constb);
  hipLaunchKernelGGL(gemm_bf16, dim3(128, 12), dim3(256), 0, stream,
                     featT, w12, b12, yzT, s12, ss12, 512, 1536, 0);
  hipLaunchKernelGGL(norm12, dim3(256, 24), dim3(256), 0, stream,
                     yzT, s12, ss12, gn1_g, gn1_b, gn2_g, gn2_b, dfeat);
  hipLaunchKernelGGL(gemm_bf16, dim3(128, 4), dim3(256), 0, stream,
                     yzT, w3, constb, y3T, s3, ss3, 1536, 512, 1);
  hipLaunchKernelGGL(norm3, dim3(256, 8), dim3(256), 0, stream,
                     y3T, s3, ss3, gn3_g, gn3_b, dmix);
}

// Round 5
// 425.936 us; speedup vs baseline: 1.5600x; 1.5600x over previous
//
#include <hip/hip_runtime.h>
#include <hip/hip_bf16.h>
#include <cstdint>
#include <cstddef>

// Problem dims
#define TN   16384   // t (feature time)
#define TFR  32768   // frame_level time
#define K1   512     // in channels
#define M12  1536    // lr (1024) + cur (512) combined out channels
#define M3   512     // final out channels

#define NSLOT 64     // atomic-spread slots per group

typedef __attribute__((ext_vector_type(8))) short short8;
typedef __attribute__((ext_vector_type(4))) float f32x4;

__device__ __forceinline__ unsigned short f2bf(float f) {
  __hip_bfloat16 h = __float2bfloat16(f);
  unsigned short u; __builtin_memcpy(&u, &h, 2); return u;
}
__device__ __forceinline__ float bf2f(unsigned short u) {
  __hip_bfloat16 h; __builtin_memcpy(&h, &u, 2); return __bfloat162float(h);
}

// ---------------------------------------------------------------------------
// Weight prep: w12 = [lr_w; cur_w] bf16 [1536][512]; w3 = prop_w[:,512:2048] bf16
// [512][1536]; b12 = [lr_b; cur_b]
// ---------------------------------------------------------------------------
__global__ void prep_w(const float* __restrict__ cur_w, const float* __restrict__ cur_b,
                       const float* __restrict__ lr_w, const float* __restrict__ lr_b,
                       const float* __restrict__ prop_w,
                       unsigned short* __restrict__ w12, unsigned short* __restrict__ w3,
                       float* __restrict__ b12) {
  int i = blockIdx.x * blockDim.x + threadIdx.x;   // 0 .. 786431
  {
    int r = i >> 9, k = i & 511;
    float v = (r < 1024) ? lr_w[i] : cur_w[(r - 1024) * 512 + k];
    w12[i] = f2bf(v);
  }
  {
    int o = i / 1536, c = i - o * 1536;
    w3[i] = f2bf(prop_w[o * 2048 + 512 + c]);
  }
  if (i < M12) b12[i] = (i < 1024) ? lr_b[i] : cur_b[i - 1024];
}

// ---------------------------------------------------------------------------
// Partial per-frame max over channel chunks: pm[chunk][t], 8 chunks of 64 ch
// ---------------------------------------------------------------------------
__global__ void maxred(const float* __restrict__ fr, float* __restrict__ pm) {
  int b = blockIdx.x;             // 1024 blocks
  int cchunk = b >> 7;            // 0..7
  int t = (b & 127) * 256 + threadIdx.x;
  int cs = cchunk * 64;
  float mx = -3.4e38f;
#pragma unroll 8
  for (int c = cs; c < cs + 64; ++c) mx = fmaxf(mx, fr[(size_t)c * TFR + t]);
  pm[(size_t)cchunk * TFR + t] = mx;
}

// ---------------------------------------------------------------------------
// Single-block scan + inverse-CDF pick: idx = first t with c[t] == min(c)
// ---------------------------------------------------------------------------
__global__ __launch_bounds__(1024) void scan_pick(const float* __restrict__ pm,
                                                  int* __restrict__ idxp) {
  __shared__ float sA[1024], sB[1024];
  __shared__ int si[1024];
  int tid = threadIdx.x;
  int base = tid * 32;
  float mv[32];
  float lsum = 0.f;
#pragma unroll
  for (int j = 0; j < 32; ++j) {
    int t = base + j;
    float mx = pm[t];
#pragma unroll
    for (int p = 1; p < 8; ++p) mx = fmaxf(mx, pm[(size_t)p * TFR + t]);
    mv[j] = mx; lsum += mx;
  }
  sA[tid] = lsum; __syncthreads();
  float* a = sA; float* b = sB;
  for (int d = 1; d < 1024; d <<= 1) {
    float v = a[tid];
    if (tid >= d) v += a[tid - d];
    b[tid] = v; __syncthreads();
    float* tmp = a; a = b; b = tmp;
  }
  float total = a[1023];
  float prev = (tid > 0) ? a[tid - 1] : 0.f;
  float inv = 1.0f / total;
  int cloc[32];
  int minc = 0x7fffffff;
  float run = prev;
#pragma unroll
  for (int j = 0; j < 32; ++j) {
    run += mv[j];
    int cj = (int)(run * inv * 16384.0f);   // trunc toward 0 (cdf >= 0)
    cloc[j] = cj;
    if (cj >= 0 && cj < minc) minc = cj;
  }
  si[tid] = minc; __syncthreads();
  for (int d = 512; d >= 1; d >>= 1) { if (tid < d) si[tid] = min(si[tid], si[tid + d]); __syncthreads(); }
  int cur = si[0]; __syncthreads();
  int cand = 0x7fffffff;
#pragma unroll
  for (int j = 0; j < 32; ++j)
    if (cloc[j] == cur && cand == 0x7fffffff) cand = base + j;
  si[tid] = cand; __syncthreads();
  for (int d = 512; d >= 1; d >>= 1) { if (tid < d) si[tid] = min(si[tid], si[tid + d]); __syncthreads(); }
  if (tid == 0) idxp[0] = si[0];
}

// ---------------------------------------------------------------------------
// const[o] = prop_b[o] + sum_{c<512} prop_w[o][c] * frame[c][idx]
// ---------------------------------------------------------------------------
__global__ void sample_const(const float* __restrict__ prop_w, const float* __restrict__ prop_b,
                             const float* __restrict__ frame, const int* __restrict__ idxp,
                             float* __restrict__ constb) {
  int o = blockIdx.x * blockDim.x + threadIdx.x;
  if (o >= 512) return;
  int idx = idxp[0];
  float acc = prop_b[o];
  for (int c = 0; c < 512; ++c)
    acc += prop_w[o * 2048 + c] * frame[(size_t)c * TFR + idx];
  constb[o] = acc;
}

// ---------------------------------------------------------------------------
// Transpose feature [512][16384] f32 -> featT [16384][512] bf16
// ---------------------------------------------------------------------------
__global__ __launch_bounds__(256) void transpose_feat(const float* __restrict__ X,
                                                      unsigned short* __restrict__ XT) {
  __shared__ float tile[64][65];
  int t0 = blockIdx.x * 64, c0 = blockIdx.y * 64;
  int tx = threadIdx.x & 63, ty = threadIdx.x >> 6;
#pragma unroll
  for (int r = 0; r < 16; ++r) {
    int c = c0 + ty * 16 + r;
    tile[ty * 16 + r][tx] = X[(size_t)c * TN + t0 + tx];
  }
  __syncthreads();
#pragma unroll
  for (int r = 0; r < 16; ++r) {
    int t = t0 + ty * 16 + r;
    XT[(size_t)t * K1 + c0 + tx] = f2bf(tile[tx][ty * 16 + r]);
  }
}

// ---------------------------------------------------------------------------
// GEMM: Y[t][c] = sum_k XT[t][k] * Wb[c][k] + bias[c]   (bf16 in, bf16 out)
// m97 structure: 128x128 tile, BK=64, global_load_lds width=16 with
// inverse-XOR-swizzled global source + XOR-swizzled ds_read (rule #21).
// Group stats accumulated via slot-spread atomics.
// ---------------------------------------------------------------------------
__global__ __launch_bounds__(256) void gemm_bf16(
    const unsigned short* __restrict__ XT,   // [T][K]
    const unsigned short* __restrict__ Wb,   // [M][K]
    const float* __restrict__ bias,          // [M]
    unsigned short* __restrict__ Y,          // [T][M]
    float* __restrict__ gsum, float* __restrict__ gss,
    int K, int M, int mode)                  // mode 0: gn2|gn1 combined; 1: gn3
{
  __shared__ __attribute__((aligned(16))) unsigned short As[128 * 64];
  __shared__ __attribute__((aligned(16))) unsigned short Bs[128 * 64];
  const int tid = threadIdx.x;
  const int lane = tid & 63;
  const int w = tid >> 6;
  const int t0 = blockIdx.x * 128;
  const int c0 = blockIdx.y * 128;

  f32x4 acc[4][4] = {};
  const int lrow = lane & 15;
  const int lk = (lane >> 4) * 8;
  const int tb = (w >> 1) * 64, cb = (w & 1) * 64;

  // Per-lane staging geometry: LDS linear offset L = w*4096 + it*1024 + lane*16.
  // row = L>>7 (128 B per row), source col pre-swizzled: colb = (L&127) ^ ((row&7)<<4)
  const int Lbase = w * 4096 + lane * 16;
  const int srow0 = Lbase >> 7;            // row for it=0 (it adds 8 rows)
  const int scolb = (Lbase & 127) ^ ((srow0 & 7) << 4);  // (row&7) invariant under +8

  for (int ks = 0; ks < K; ks += 64) {
    __syncthreads();
#pragma unroll
    for (int it = 0; it < 4; ++it) {
      int row = srow0 + it * 8;
      const char* ga = (const char*)(XT + (size_t)(t0 + row) * K + ks) + scolb;
      const char* gb = (const char*)(Wb + (size_t)(c0 + row) * K + ks) + scolb;
      char* la = (char*)As + w * 4096 + it * 1024;
      char* lb = (char*)Bs + w * 4096 + it * 1024;
      __builtin_amdgcn_global_load_lds(
          (const __attribute__((address_space(1))) unsigned int*)ga,
          (__attribute__((address_space(3))) unsigned int*)la, 16, 0, 0);
      __builtin_amdgcn_global_load_lds(
          (const __attribute__((address_space(1))) unsigned int*)gb,
          (__attribute__((address_space(3))) unsigned int*)lb, 16, 0, 0);
    }
    __syncthreads();
#pragma unroll
    for (int kk = 0; kk < 64; kk += 32) {
      short8 a[4], b[4];
#pragma unroll
      for (int i = 0; i < 4; ++i) {
        int r = tb + i * 16 + lrow;
        int cbyte = ((kk + lk) * 2) ^ ((r & 7) << 4);
        a[i] = *(const short8*)((const char*)As + r * 128 + cbyte);
      }
#pragma unroll
      for (int j = 0; j < 4; ++j) {
        int r = cb + j * 16 + lrow;
        int cbyte = ((kk + lk) * 2) ^ ((r & 7) << 4);
        b[j] = *(const short8*)((const char*)Bs + r * 128 + cbyte);
      }
#pragma unroll
      for (int i = 0; i < 4; ++i)
#pragma unroll
        for (int j = 0; j < 4; ++j)
          acc[i][j] = __builtin_amdgcn_mfma_f32_16x16x32_bf16(a[i], b[j], acc[i][j], 0, 0, 0);
    }
  }

  // epilogue: bias, bf16 store, group stats (slot-spread atomics)
  const int lq = (lane >> 4) * 4;
  const int slot = blockIdx.x & (NSLOT - 1);
#pragma unroll
  for (int j = 0; j < 4; ++j) {
    int c = c0 + cb + j * 16 + lrow;
    float bv = bias[c];
    float s = 0.f, ss = 0.f;
#pragma unroll
    for (int i = 0; i < 4; ++i) {
#pragma unroll
      for (int q = 0; q < 4; ++q) {
        float v = acc[i][j][q] + bv;
        s += v; ss += v * v;
        int t = t0 + tb + i * 16 + lq + q;
        Y[(size_t)t * M + c] = f2bf(v);
      }
    }
#pragma unroll
    for (int off = 32; off >= 1; off >>= 1) { s += __shfl_xor(s, off); ss += __shfl_xor(ss, off); }
    if (lane == 0) {
      int g = (mode == 0) ? ((c < 1024) ? (c >> 5) : (32 + ((c - 1024) >> 4))) : (c >> 4);
      atomicAdd(&gsum[g * NSLOT + slot], s);
      atomicAdd(&gss[g * NSLOT + slot], ss);
    }
  }
}

// ---------------------------------------------------------------------------
// Normalize conv1+2 output: in-place relu(norm(yz)) (bf16, GEMM3 input) and
// transposed f32 write of channels <1024 (feat) to d_out.
// ---------------------------------------------------------------------------
__global__ __launch_bounds__(256) void norm12(
    unsigned short* __restrict__ yz,      // [T][1536]
    const float* __restrict__ gsum, const float* __restrict__ gss,
    const float* __restrict__ gn1_g, const float* __restrict__ gn1_b,
    const float* __restrict__ gn2_g, const float* __restrict__ gn2_b,
    float* __restrict__ dfeat) {          // [1024][16384]
  __shared__ float tile[64][65];
  int t0 = blockIdx.x * 64, c0 = blockIdx.y * 64;
  int tx = threadIdx.x & 63, ty = threadIdx.x >> 6;
  int c = c0 + tx;
  int g; float gm, gb, cnt;
  if (c < 1024) { g = c >> 5;               gm = gn2_g[c];        gb = gn2_b[c];        cnt = 524288.f; }
  else          { g = 32 + ((c - 1024) >> 4); gm = gn1_g[c - 1024]; gb = gn1_b[c - 1024]; cnt = 262144.f; }
  float s = 0.f, q = 0.f;
#pragma unroll
  for (int i = 0; i < NSLOT; ++i) { s += gsum[g * NSLOT + i]; q += gss[g * NSLOT + i]; }
  float mean = s / cnt;
  float var = q / cnt - mean * mean;
  float rstd = rsqrtf(var + 1e-5f);
#pragma unroll
  for (int r = 0; r < 16; ++r) {
    int t = t0 + ty * 16 + r;
    size_t off = (size_t)t * 1536 + c;
    float v = bf2f(yz[off]);
    v = (v - mean) * rstd * gm + gb;
    v = fmaxf(v, 0.f);
    yz[off] = f2bf(v);
    tile[tx][ty * 16 + r] = v;
  }
  if (c0 < 1024) {
    __syncthreads();
#pragma unroll
    for (int r = 0; r < 16; ++r) {
      int cc = c0 + ty * 16 + r;
      dfeat[(size_t)cc * TN + t0 + tx] = tile[ty * 16 + r][tx];
    }
  }
}

// ---------------------------------------------------------------------------
// Normalize conv3 output -> mixed (f32, transposed to [512][16384])
// ---------------------------------------------------------------------------
__global__ __launch_bounds__(256) void norm3(
    const unsigned short* __restrict__ y3,  // [T][512]
    const float* __restrict__ gsum, const float* __restrict__ gss,
    const float* __restrict__ g3g, const float* __restrict__ g3b,
    float* __restrict__ dmix) {             // [512][16384]
  __shared__ float tile[64][65];
  int t0 = blockIdx.x * 64, c0 = blockIdx.y * 64;
  int tx = threadIdx.x & 63, ty = threadIdx.x >> 6;
  int c = c0 + tx;
  int g = c >> 4;
  float s = 0.f, q = 0.f;
#pragma unroll
  for (int i = 0; i < NSLOT; ++i) { s += gsum[g * NSLOT + i]; q += gss[g * NSLOT + i]; }
  float mean = s / 262144.f;
  float var = q / 262144.f - mean * mean;
  float rstd = rsqrtf(var + 1e-5f);
  float gm = g3g[c], gb = g3b[c];
#pragma unroll
  for (int r = 0; r < 16; ++r) {
    int t = t0 + ty * 16 + r;
    float v = bf2f(y3[(size_t)t * 512 + c]);
    v = (v - mean) * rstd * gm + gb;
    tile[tx][ty * 16 + r] = fmaxf(v, 0.f);
  }
  __syncthreads();
#pragma unroll
  for (int r = 0; r < 16; ++r) {
    int cc = c0 + ty * 16 + r;
    dmix[(size_t)cc * TN + t0 + tx] = tile[ty * 16 + r][tx];
  }
}

// ---------------------------------------------------------------------------
extern "C" void kernel_launch(void* const* d_in, const int* in_sizes, int n_in,
                              void* d_out, int out_size, void* d_ws, size_t ws_size,
                              hipStream_t stream) {
  const float* feature = (const float*)d_in[0];
  const float* frame   = (const float*)d_in[1];
  const float* cur_w   = (const float*)d_in[2];
  const float* cur_b   = (const float*)d_in[3];
  const float* gn1_g   = (const float*)d_in[4];
  const float* gn1_b   = (const float*)d_in[5];
  const float* lr_w    = (const float*)d_in[6];
  const float* lr_b    = (const float*)d_in[7];
  const float* gn2_g   = (const float*)d_in[8];
  const float* gn2_b   = (const float*)d_in[9];
  const float* prop_w  = (const float*)d_in[10];
  const float* prop_b  = (const float*)d_in[11];
  const float* gn3_g   = (const float*)d_in[12];
  const float* gn3_b   = (const float*)d_in[13];

  char* ws = (char*)d_ws;
  // ws layout (bytes)
  unsigned short* yzT   = (unsigned short*)(ws);                 // 50331648: conv12 raw -> z (in-place)
  unsigned short* featT = (unsigned short*)(ws + 50331648);      // 16777216: featT, reused as y3T
  unsigned short* y3T   = featT;
  unsigned short* w12   = (unsigned short*)(ws + 67108864);      // 1572864
  unsigned short* w3    = (unsigned short*)(ws + 68681728);      // 1572864
  float* b12    = (float*)(ws + 70254592);                       // 6144
  float* pm     = (float*)(ws + 70260736);                       // 1048576
  float* s12    = (float*)(ws + 71309312);                       // 64*64 f32 = 16384 B
  float* ss12   = s12 + 64 * NSLOT;                              // 16384 B
  float* s3     = (float*)(ws + 71342080);                       // 32*64 f32 = 8192 B
  float* ss3    = s3 + 32 * NSLOT;                               // 8192 B
  float* constb = (float*)(ws + 71358464);                       // 2048
  int*   idxp   = (int*)(ws + 71360512);

  float* dmix  = (float*)d_out;                 // [512][16384]
  float* dfeat = (float*)d_out + 8388608;       // [1024][16384]

  // zero the stats accumulators (ws is poisoned each launch)
  hipMemsetAsync(ws + 71309312, 0, 49152, stream);

  hipLaunchKernelGGL(prep_w, dim3(3072), dim3(256), 0, stream,
                     cur_w, cur_b, lr_w, lr_b, prop_w, w12, w3, b12);
  hipLaunchKernelGGL(maxred, dim3(1024), dim3(256), 0, stream, frame, pm);
  hipLaunchKernelGGL(scan_pick, dim3(1), dim3(1024), 0, stream, pm, idxp);
  hipLaunchKernelGGL(transpose_feat, dim3(256, 8), dim3(256), 0, stream, feature, featT);
  hipLaunchKernelGGL(sample_const, dim3(2), dim3(256), 0, stream,
                     prop_w, prop_b, frame, idxp, constb);
  hipLaunchKernelGGL(gemm_bf16, dim3(128, 12), dim3(256), 0, stream,
                     featT, w12, b12, yzT, s12, ss12, 512, 1536, 0);
  hipLaunchKernelGGL(norm12, dim3(256, 24), dim3(256), 0, stream,
                     yzT, s12, ss12, gn1_g, gn1_b, gn2_g, gn2_b, dfeat);
  hipLaunchKernelGGL(gemm_bf16, dim3(128, 4), dim3(256), 0, stream,
                     yzT, w3, constb, y3T, s3, ss3, 1536, 512, 1);
  hipLaunchKernelGGL(norm3, dim3(256, 8), dim3(256), 0, stream,
                     y3T, s3, ss3, gn3_g, gn3_b, dmix);
}

// Round 12
// 380.564 us; speedup vs baseline: 1.7460x; 1.1192x over previous
//
#include <hip/hip_runtime.h>
#include <hip/hip_bf16.h>
#include <cstdint>
#include <cstddef>

// Problem dims
#define TN   16384   // t (feature time)
#define TFR  32768   // frame_level time
#define K1   512     // in channels
#define M12  1536    // lr (1024) + cur (512) combined out channels
#define M3   512     // final out channels

#define NSLOT 64     // atomic-spread slots per group

typedef __attribute__((ext_vector_type(8))) short short8;
typedef __attribute__((ext_vector_type(4))) float f32x4;

__device__ __forceinline__ unsigned short f2bf(float f) {
  __hip_bfloat16 h = __float2bfloat16(f);
  unsigned short u; __builtin_memcpy(&u, &h, 2); return u;
}
__device__ __forceinline__ float bf2f(unsigned short u) {
  __hip_bfloat16 h; __builtin_memcpy(&h, &u, 2); return __bfloat162float(h);
}

// ---------------------------------------------------------------------------
// Weight prep: w12 = [lr_w; cur_w] bf16 [1536][512]; w3 = prop_w[:,512:2048] bf16
// [512][1536]; b12 = [lr_b; cur_b]
// ---------------------------------------------------------------------------
__global__ void prep_w(const float* __restrict__ cur_w, const float* __restrict__ cur_b,
                       const float* __restrict__ lr_w, const float* __restrict__ lr_b,
                       const float* __restrict__ prop_w,
                       unsigned short* __restrict__ w12, unsigned short* __restrict__ w3,
                       float* __restrict__ b12) {
  int i = blockIdx.x * blockDim.x + threadIdx.x;   // 0 .. 786431
  {
    int r = i >> 9, k = i & 511;
    float v = (r < 1024) ? lr_w[i] : cur_w[(r - 1024) * 512 + k];
    w12[i] = f2bf(v);
  }
  {
    int o = i / 1536, c = i - o * 1536;
    w3[i] = f2bf(prop_w[o * 2048 + 512 + c]);
  }
  if (i < M12) b12[i] = (i < 1024) ? lr_b[i] : cur_b[i - 1024];
}

// ---------------------------------------------------------------------------
// Partial per-frame max over channel chunks: pm[chunk][t], 8 chunks of 64 ch.
// float4-vectorized: 256 blocks, each thread owns 4 consecutive t.
// ---------------------------------------------------------------------------
__global__ void maxred(const float* __restrict__ fr, float* __restrict__ pm) {
  int b = blockIdx.x;             // 256 blocks
  int cchunk = b >> 5;            // 0..7
  int t = (b & 31) * 1024 + threadIdx.x * 4;
  int cs = cchunk * 64;
  float4 mx = make_float4(-3.4e38f, -3.4e38f, -3.4e38f, -3.4e38f);
#pragma unroll 8
  for (int c = cs; c < cs + 64; ++c) {
    float4 v = *(const float4*)(fr + (size_t)c * TFR + t);
    mx.x = fmaxf(mx.x, v.x); mx.y = fmaxf(mx.y, v.y);
    mx.z = fmaxf(mx.z, v.z); mx.w = fmaxf(mx.w, v.w);
  }
  *(float4*)(pm + (size_t)cchunk * TFR + t) = mx;
}

// ---------------------------------------------------------------------------
// Single-block scan + inverse-CDF pick: idx = first t with c[t] == min(c)
// ---------------------------------------------------------------------------
__global__ __launch_bounds__(1024) void scan_pick(const float* __restrict__ pm,
                                                  int* __restrict__ idxp) {
  __shared__ float sA[1024], sB[1024];
  __shared__ int si[1024];
  int tid = threadIdx.x;
  int base = tid * 32;
  float mv[32];
  float lsum = 0.f;
#pragma unroll
  for (int j = 0; j < 32; ++j) {
    int t = base + j;
    float mx = pm[t];
#pragma unroll
    for (int p = 1; p < 8; ++p) mx = fmaxf(mx, pm[(size_t)p * TFR + t]);
    mv[j] = mx; lsum += mx;
  }
  sA[tid] = lsum; __syncthreads();
  float* a = sA; float* b = sB;
  for (int d = 1; d < 1024; d <<= 1) {
    float v = a[tid];
    if (tid >= d) v += a[tid - d];
    b[tid] = v; __syncthreads();
    float* tmp = a; a = b; b = tmp;
  }
  float total = a[1023];
  float prev = (tid > 0) ? a[tid - 1] : 0.f;
  float inv = 1.0f / total;
  int cloc[32];
  int minc = 0x7fffffff;
  float run = prev;
#pragma unroll
  for (int j = 0; j < 32; ++j) {
    run += mv[j];
    int cj = (int)(run * inv * 16384.0f);   // trunc toward 0 (cdf >= 0)
    cloc[j] = cj;
    if (cj >= 0 && cj < minc) minc = cj;
  }
  si[tid] = minc; __syncthreads();
  for (int d = 512; d >= 1; d >>= 1) { if (tid < d) si[tid] = min(si[tid], si[tid + d]); __syncthreads(); }
  int cur = si[0]; __syncthreads();
  int cand = 0x7fffffff;
#pragma unroll
  for (int j = 0; j < 32; ++j)
    if (cloc[j] == cur && cand == 0x7fffffff) cand = base + j;
  si[tid] = cand; __syncthreads();
  for (int d = 512; d >= 1; d >>= 1) { if (tid < d) si[tid] = min(si[tid], si[tid + d]); __syncthreads(); }
  if (tid == 0) idxp[0] = si[0];
}

// ---------------------------------------------------------------------------
// const[o] = prop_b[o] + sum_{c<512} prop_w[o][c] * frame[c][idx]
// 32 blocks x 256 threads; 16 outputs/block, 16 lanes per output, float4 reads.
// ---------------------------------------------------------------------------
__global__ __launch_bounds__(256) void sample_const(
    const float* __restrict__ prop_w, const float* __restrict__ prop_b,
    const float* __restrict__ frame, const int* __restrict__ idxp,
    float* __restrict__ constb) {
  __shared__ float sfr[512];
  int tid = threadIdx.x;
  int idx = idxp[0];
  for (int c = tid; c < 512; c += 256) sfr[c] = frame[(size_t)c * TFR + idx];
  __syncthreads();
  int o = blockIdx.x * 16 + (tid >> 4);
  int cl = tid & 15;
  float acc = 0.f;
#pragma unroll
  for (int i = 0; i < 8; ++i) {
    int c = i * 64 + cl * 4;
    float4 wv = *(const float4*)(prop_w + (size_t)o * 2048 + c);
    acc += wv.x * sfr[c] + wv.y * sfr[c + 1] + wv.z * sfr[c + 2] + wv.w * sfr[c + 3];
  }
#pragma unroll
  for (int off = 8; off >= 1; off >>= 1) acc += __shfl_xor(acc, off);
  if (cl == 0) constb[o] = acc + prop_b[o];
}

// ---------------------------------------------------------------------------
// Transpose feature [512][16384] f32 -> featT [16384][512] bf16 (ushort4 writes)
// ---------------------------------------------------------------------------
__global__ __launch_bounds__(256) void transpose_feat(const float* __restrict__ X,
                                                      unsigned short* __restrict__ XT) {
  __shared__ float tile[64][65];
  int t0 = blockIdx.x * 64, c0 = blockIdx.y * 64;
  int tx = threadIdx.x & 63, ty = threadIdx.x >> 6;
#pragma unroll
  for (int r = 0; r < 16; ++r) {
    int c = c0 + ty * 16 + r;
    tile[ty * 16 + r][tx] = X[(size_t)c * TN + t0 + tx];
  }
  __syncthreads();
  int c4 = (threadIdx.x & 15) * 4;
  int tl0 = threadIdx.x >> 4;   // 0..15
#pragma unroll
  for (int p = 0; p < 4; ++p) {
    int tl = tl0 + p * 16;
    ushort4 o;
    o.x = f2bf(tile[c4 + 0][tl]);
    o.y = f2bf(tile[c4 + 1][tl]);
    o.z = f2bf(tile[c4 + 2][tl]);
    o.w = f2bf(tile[c4 + 3][tl]);
    *(ushort4*)(XT + (size_t)(t0 + tl) * K1 + c0 + c4) = o;
  }
}

// ---------------------------------------------------------------------------
// GEMM: Y[t][c] = sum_k XT[t][k] * Wb[c][k] + bias[c]   (bf16 in, bf16 out)
// m97 structure: 128x128 tile, BK=64, global_load_lds width=16 with
// inverse-XOR-swizzled global source + XOR-swizzled ds_read (rule #21).
// Group stats accumulated via slot-spread atomics.  (UNCHANGED from R1)
// ---------------------------------------------------------------------------
__global__ __launch_bounds__(256) void gemm_bf16(
    const unsigned short* __restrict__ XT,   // [T][K]
    const unsigned short* __restrict__ Wb,   // [M][K]
    const float* __restrict__ bias,          // [M]
    unsigned short* __restrict__ Y,          // [T][M]
    float* __restrict__ gsum, float* __restrict__ gss,
    int K, int M, int mode)                  // mode 0: gn2|gn1 combined; 1: gn3
{
  __shared__ __attribute__((aligned(16))) unsigned short As[128 * 64];
  __shared__ __attribute__((aligned(16))) unsigned short Bs[128 * 64];
  const int tid = threadIdx.x;
  const int lane = tid & 63;
  const int w = tid >> 6;
  const int t0 = blockIdx.x * 128;
  const int c0 = blockIdx.y * 128;

  f32x4 acc[4][4] = {};
  const int lrow = lane & 15;
  const int lk = (lane >> 4) * 8;
  const int tb = (w >> 1) * 64, cb = (w & 1) * 64;

  const int Lbase = w * 4096 + lane * 16;
  const int srow0 = Lbase >> 7;
  const int scolb = (Lbase & 127) ^ ((srow0 & 7) << 4);

  for (int ks = 0; ks < K; ks += 64) {
    __syncthreads();
#pragma unroll
    for (int it = 0; it < 4; ++it) {
      int row = srow0 + it * 8;
      const char* ga = (const char*)(XT + (size_t)(t0 + row) * K + ks) + scolb;
      const char* gb = (const char*)(Wb + (size_t)(c0 + row) * K + ks) + scolb;
      char* la = (char*)As + w * 4096 + it * 1024;
      char* lb = (char*)Bs + w * 4096 + it * 1024;
      __builtin_amdgcn_global_load_lds(
          (const __attribute__((address_space(1))) unsigned int*)ga,
          (__attribute__((address_space(3))) unsigned int*)la, 16, 0, 0);
      __builtin_amdgcn_global_load_lds(
          (const __attribute__((address_space(1))) unsigned int*)gb,
          (__attribute__((address_space(3))) unsigned int*)lb, 16, 0, 0);
    }
    __syncthreads();
#pragma unroll
    for (int kk = 0; kk < 64; kk += 32) {
      short8 a[4], b[4];
#pragma unroll
      for (int i = 0; i < 4; ++i) {
        int r = tb + i * 16 + lrow;
        int cbyte = ((kk + lk) * 2) ^ ((r & 7) << 4);
        a[i] = *(const short8*)((const char*)As + r * 128 + cbyte);
      }
#pragma unroll
      for (int j = 0; j < 4; ++j) {
        int r = cb + j * 16 + lrow;
        int cbyte = ((kk + lk) * 2) ^ ((r & 7) << 4);
        b[j] = *(const short8*)((const char*)Bs + r * 128 + cbyte);
      }
#pragma unroll
      for (int i = 0; i < 4; ++i)
#pragma unroll
        for (int j = 0; j < 4; ++j)
          acc[i][j] = __builtin_amdgcn_mfma_f32_16x16x32_bf16(a[i], b[j], acc[i][j], 0, 0, 0);
    }
  }

  const int lq = (lane >> 4) * 4;
  const int slot = blockIdx.x & (NSLOT - 1);
#pragma unroll
  for (int j = 0; j < 4; ++j) {
    int c = c0 + cb + j * 16 + lrow;
    float bv = bias[c];
    float s = 0.f, ss = 0.f;
#pragma unroll
    for (int i = 0; i < 4; ++i) {
#pragma unroll
      for (int q = 0; q < 4; ++q) {
        float v = acc[i][j][q] + bv;
        s += v; ss += v * v;
        int t = t0 + tb + i * 16 + lq + q;
        Y[(size_t)t * M + c] = f2bf(v);
      }
    }
#pragma unroll
    for (int off = 32; off >= 1; off >>= 1) { s += __shfl_xor(s, off); ss += __shfl_xor(ss, off); }
    if (lane == 0) {
      int g = (mode == 0) ? ((c < 1024) ? (c >> 5) : (32 + ((c - 1024) >> 4))) : (c >> 4);
      atomicAdd(&gsum[g * NSLOT + slot], s);
      atomicAdd(&gss[g * NSLOT + slot], ss);
    }
  }
}

// ---------------------------------------------------------------------------
// Slot reduction -> per-group mean/rstd (hoisted out of the norm kernels)
// ---------------------------------------------------------------------------
__global__ void finalize12(const float* __restrict__ gsum, const float* __restrict__ gss,
                           float* __restrict__ mr) {   // mr[0:64]=mean, mr[64:128]=rstd
  int g = threadIdx.x;   // 64 threads
  float s = 0.f, q = 0.f;
#pragma unroll
  for (int i = 0; i < NSLOT; ++i) { s += gsum[g * NSLOT + i]; q += gss[g * NSLOT + i]; }
  float cnt = (g < 32) ? 524288.f : 262144.f;
  float mean = s / cnt;
  float var = q / cnt - mean * mean;
  mr[g] = mean;
  mr[64 + g] = rsqrtf(var + 1e-5f);
}

__global__ void finalize3(const float* __restrict__ gsum, const float* __restrict__ gss,
                          float* __restrict__ mr) {    // mr[0:32]=mean, mr[32:64]=rstd
  int g = threadIdx.x;   // 32 threads
  float s = 0.f, q = 0.f;
#pragma unroll
  for (int i = 0; i < NSLOT; ++i) { s += gsum[g * NSLOT + i]; q += gss[g * NSLOT + i]; }
  float mean = s / 262144.f;
  float var = q / 262144.f - mean * mean;
  mr[g] = mean;
  mr[32 + g] = rsqrtf(var + 1e-5f);
}

// ---------------------------------------------------------------------------
// Normalize conv1+2 output (vectorized): in-place relu(norm(yz)) (bf16, short8)
// and transposed f32 write of channels <1024 (feat) to d_out (float4).
// ---------------------------------------------------------------------------
__global__ __launch_bounds__(256) void norm12(
    unsigned short* __restrict__ yz,      // [T][1536]
    const float* __restrict__ mr,         // mean[64], rstd[64]
    const float* __restrict__ gn1_g, const float* __restrict__ gn1_b,
    const float* __restrict__ gn2_g, const float* __restrict__ gn2_b,
    float* __restrict__ dfeat) {          // [1024][16384]
  __shared__ float tile[64][65];
  __shared__ float sgm[64], sgb[64], smean[64], srstd[64];
  int t0 = blockIdx.x * 64, c0 = blockIdx.y * 64;
  int tid = threadIdx.x;
  if (tid < 64) {
    int c = c0 + tid;
    int g; float gm, gb;
    if (c < 1024) { g = c >> 5;                gm = gn2_g[c];        gb = gn2_b[c]; }
    else          { g = 32 + ((c - 1024) >> 4); gm = gn1_g[c - 1024]; gb = gn1_b[c - 1024]; }
    sgm[tid] = gm; sgb[tid] = gb; smean[tid] = mr[g]; srstd[tid] = mr[64 + g];
  }
  __syncthreads();
  int c8 = (tid & 7) * 8;
  int tl0 = tid >> 3;            // 0..31
#pragma unroll
  for (int p = 0; p < 2; ++p) {
    int tl = tl0 + p * 32;
    size_t off = (size_t)(t0 + tl) * 1536 + c0 + c8;
    short8 v = *(const short8*)(yz + off);
    short8 o;
#pragma unroll
    for (int e = 0; e < 8; ++e) {
      int cl = c8 + e;
      float f = bf2f((unsigned short)v[e]);
      f = fmaxf((f - smean[cl]) * srstd[cl] * sgm[cl] + sgb[cl], 0.f);
      o[e] = (short)f2bf(f);
      tile[cl][tl] = f;
    }
    *(short8*)(yz + off) = o;
  }
  if (c0 < 1024) {
    __syncthreads();
    int t4 = (tid & 15) * 4;
    int cl0 = tid >> 4;          // 0..15
#pragma unroll
    for (int p = 0; p < 4; ++p) {
      int cl = cl0 + p * 16;
      float4 w;
      w.x = tile[cl][t4 + 0]; w.y = tile[cl][t4 + 1];
      w.z = tile[cl][t4 + 2]; w.w = tile[cl][t4 + 3];
      *(float4*)(dfeat + (size_t)(c0 + cl) * TN + t0 + t4) = w;
    }
  }
}

// ---------------------------------------------------------------------------
// Normalize conv3 output (vectorized) -> mixed (f32, transposed to [512][16384])
// ---------------------------------------------------------------------------
__global__ __launch_bounds__(256) void norm3(
    const unsigned short* __restrict__ y3,  // [T][512]
    const float* __restrict__ mr,           // mean[32], rstd[32]
    const float* __restrict__ g3g, const float* __restrict__ g3b,
    float* __restrict__ dmix) {             // [512][16384]
  __shared__ float tile[64][65];
  __shared__ float sgm[64], sgb[64], smean[64], srstd[64];
  int t0 = blockIdx.x * 64, c0 = blockIdx.y * 64;
  int tid = threadIdx.x;
  if (tid < 64) {
    int c = c0 + tid;
    int g = c >> 4;
    sgm[tid] = g3g[c]; sgb[tid] = g3b[c]; smean[tid] = mr[g]; srstd[tid] = mr[32 + g];
  }
  __syncthreads();
  int c8 = (tid & 7) * 8;
  int tl0 = tid >> 3;
#pragma unroll
  for (int p = 0; p < 2; ++p) {
    int tl = tl0 + p * 32;
    short8 v = *(const short8*)(y3 + (size_t)(t0 + tl) * 512 + c0 + c8);
#pragma unroll
    for (int e = 0; e < 8; ++e) {
      int cl = c8 + e;
      float f = bf2f((unsigned short)v[e]);
      tile[cl][tl] = fmaxf((f - smean[cl]) * srstd[cl] * sgm[cl] + sgb[cl], 0.f);
    }
  }
  __syncthreads();
  int t4 = (tid & 15) * 4;
  int cl0 = tid >> 4;
#pragma unroll
  for (int p = 0; p < 4; ++p) {
    int cl = cl0 + p * 16;
    float4 w;
    w.x = tile[cl][t4 + 0]; w.y = tile[cl][t4 + 1];
    w.z = tile[cl][t4 + 2]; w.w = tile[cl][t4 + 3];
    *(float4*)(dmix + (size_t)(c0 + cl) * TN + t0 + t4) = w;
  }
}

// ---------------------------------------------------------------------------
extern "C" void kernel_launch(void* const* d_in, const int* in_sizes, int n_in,
                              void* d_out, int out_size, void* d_ws, size_t ws_size,
                              hipStream_t stream) {
  const float* feature = (const float*)d_in[0];
  const float* frame   = (const float*)d_in[1];
  const float* cur_w   = (const float*)d_in[2];
  const float* cur_b   = (const float*)d_in[3];
  const float* gn1_g   = (const float*)d_in[4];
  const float* gn1_b   = (const float*)d_in[5];
  const float* lr_w    = (const float*)d_in[6];
  const float* lr_b    = (const float*)d_in[7];
  const float* gn2_g   = (const float*)d_in[8];
  const float* gn2_b   = (const float*)d_in[9];
  const float* prop_w  = (const float*)d_in[10];
  const float* prop_b  = (const float*)d_in[11];
  const float* gn3_g   = (const float*)d_in[12];
  const float* gn3_b   = (const float*)d_in[13];

  char* ws = (char*)d_ws;
  unsigned short* yzT   = (unsigned short*)(ws);                 // 50331648
  unsigned short* featT = (unsigned short*)(ws + 50331648);      // 16777216 (reused as y3T)
  unsigned short* y3T   = featT;
  unsigned short* w12   = (unsigned short*)(ws + 67108864);      // 1572864
  unsigned short* w3    = (unsigned short*)(ws + 68681728);      // 1572864
  float* b12    = (float*)(ws + 70254592);                       // 6144
  float* pm     = (float*)(ws + 70260736);                       // 1048576
  float* s12    = (float*)(ws + 71309312);                       // 64*64 f32
  float* ss12   = s12 + 64 * NSLOT;
  float* s3     = (float*)(ws + 71342080);                       // 32*64 f32
  float* ss3    = s3 + 32 * NSLOT;
  float* constb = (float*)(ws + 71358464);                       // 2048
  int*   idxp   = (int*)(ws + 71360512);
  float* mr12   = (float*)(ws + 71360576);                       // 128 f32
  float* mr3    = (float*)(ws + 71361088);                       // 64 f32

  float* dmix  = (float*)d_out;                 // [512][16384]
  float* dfeat = (float*)d_out + 8388608;       // [1024][16384]

  hipMemsetAsync(ws + 71309312, 0, 49152, stream);

  hipLaunchKernelGGL(prep_w, dim3(3072), dim3(256), 0, stream,
                     cur_w, cur_b, lr_w, lr_b, prop_w, w12, w3, b12);
  hipLaunchKernelGGL(maxred, dim3(256), dim3(256), 0, stream, frame, pm);
  hipLaunchKernelGGL(scan_pick, dim3(1), dim3(1024), 0, stream, pm, idxp);
  hipLaunchKernelGGL(transpose_feat, dim3(256, 8), dim3(256), 0, stream, feature, featT);
  hipLaunchKernelGGL(sample_const, dim3(32), dim3(256), 0, stream,
                     prop_w, prop_b, frame, idxp, constb);
  hipLaunchKernelGGL(gemm_bf16, dim3(128, 12), dim3(256), 0, stream,
                     featT, w12, b12, yzT, s12, ss12, 512, 1536, 0);
  hipLaunchKernelGGL(finalize12, dim3(1), dim3(64), 0, stream, s12, ss12, mr12);
  hipLaunchKernelGGL(norm12, dim3(256, 24), dim3(256), 0, stream,
                     yzT, mr12, gn1_g, gn1_b, gn2_g, gn2_b, dfeat);
  hipLaunchKernelGGL(gemm_bf16, dim3(128, 4), dim3(256), 0, stream,
                     yzT, w3, constb, y3T, s3, ss3, 1536, 512, 1);
  hipLaunchKernelGGL(finalize3, dim3(1), dim3(32), 0, stream, s3, ss3, mr3);
  hipLaunchKernelGGL(norm3, dim3(256, 8), dim3(256), 0, stream,
                     y3T, mr3, gn3_g, gn3_b, dmix);
}